// Round 2
// baseline (299.196 us; speedup 1.0000x reference)
//
#include <hip/hip_runtime.h>
#include <stdint.h>

#define M_NODES 2048
#define KSEL 16

typedef unsigned int u32;

// ---- stage [2048,3] f32 -> LDS float4 (w=0) ----
__device__ __forceinline__ void stage_nodes(const float* __restrict__ src,
                                            float4* dst) {
  for (int i = threadIdx.x; i < M_NODES; i += blockDim.x) {
    dst[i] = make_float4(src[3 * i + 0], src[3 * i + 1], src[3 * i + 2], 0.0f);
  }
}

// ---- per-lane exact top-16 by packed key (d2 bits | index) ----
// key = (f32bits(d2) & 0xFFFFF800) | j ; positive-float bits are order-
// preserving, low 11 bits = node index (ties -> lowest index, like top_k).
__device__ __forceinline__ void select_top16(float px, float py, float pz,
                                             const float4* sn, u32 a[KSEL]) {
#pragma unroll
  for (int t = 0; t < KSEL; ++t) a[t] = 0xFFFFFFFFu;
  for (int j = 0; j < M_NODES; j += 4) {
#pragma unroll
    for (int u = 0; u < 4; ++u) {
      float4 n = sn[j + u];
      float dx = px - n.x, dy = py - n.y, dz = pz - n.z;
      float d2 = fmaf(dx, dx, fmaf(dy, dy, dz * dz));
      u32 key = (__float_as_uint(d2) & 0xFFFFF800u) | (u32)(j + u);
      if (key < a[KSEL - 1]) {
        // sorted insert, branch-free body: a[t] = min(max(a[t-1],key), a[t])
#pragma unroll
        for (int t = KSEL - 1; t >= 1; --t) {
          u32 lo = a[t - 1];
          u32 mx = lo > key ? lo : key;
          a[t] = mx < a[t] ? mx : a[t];
        }
        a[0] = key < a[0] ? key : a[0];
      }
    }
  }
}

__device__ __forceinline__ float key_to_dist(u32 k) {
  float v = sqrtf(__uint_as_float(k & 0xFFFFF800u));
  return fmaxf(v, 1e-6f);
}

// ---- kernel 1: top-16 selection, spill keys, accumulate global sum ----
template <bool STORE>
__global__ __launch_bounds__(256) void k_select(
    const float* __restrict__ means, const float* __restrict__ nodes,
    u32* __restrict__ keys_out, float* __restrict__ sum_ptr, int N) {
  __shared__ float4 sn[M_NODES];
  stage_nodes(nodes, sn);
  __syncthreads();

  int n = blockIdx.x * blockDim.x + threadIdx.x;
  float px = means[3 * n + 0];
  float py = means[3 * n + 1];
  float pz = means[3 * n + 2];

  u32 a[KSEL];
  select_top16(px, py, pz, sn, a);

  if (STORE) {
    u32* kp = keys_out + (size_t)n * KSEL;
#pragma unroll
    for (int t = 0; t < KSEL; t += 4) {
      *reinterpret_cast<uint4*>(kp + t) =
          make_uint4(a[t], a[t + 1], a[t + 2], a[t + 3]);
    }
  }

  float s = 0.0f;
#pragma unroll
  for (int t = 0; t < KSEL; ++t) s += key_to_dist(a[t]);
#pragma unroll
  for (int off = 32; off > 0; off >>= 1) s += __shfl_xor(s, off);
  if ((threadIdx.x & 63) == 0) atomicAdd(sum_ptr, s);
}

// ---- kernel 2: global scale -> softmax -> gather offsets -> output ----
template <bool RELOAD>
__global__ __launch_bounds__(256) void k_finish(
    const float* __restrict__ means, const float* __restrict__ nodes,
    const float* __restrict__ noffs, const int* __restrict__ tptr,
    const u32* __restrict__ keys, const float* __restrict__ sum_ptr,
    float* __restrict__ out, int N) {
  __shared__ float4 so[M_NODES];
  int ti = *tptr;
  stage_nodes(noffs + (size_t)ti * (3 * M_NODES), so);

  int n = blockIdx.x * blockDim.x + threadIdx.x;
  float px = means[3 * n + 0];
  float py = means[3 * n + 1];
  float pz = means[3 * n + 2];

  u32 a[KSEL];
  if constexpr (!RELOAD) {
    __shared__ float4 sn[M_NODES];
    stage_nodes(nodes, sn);
    __syncthreads();
    select_top16(px, py, pz, sn, a);
  } else {
    __syncthreads();
    const uint4* kp = reinterpret_cast<const uint4*>(keys + (size_t)n * KSEL);
#pragma unroll
    for (int t = 0; t < 4; ++t) {
      uint4 v = kp[t];
      a[4 * t + 0] = v.x; a[4 * t + 1] = v.y;
      a[4 * t + 2] = v.z; a[4 * t + 3] = v.w;
    }
  }

  float scale = (*sum_ptr) * (1.0f / ((float)N * (float)KSEL)) + 1e-6f;
  float inv = 1.0f / scale;
  float vmin = key_to_dist(a[0]);  // a[] sorted ascending -> a[0] is min

  float wsum = 0.0f, mx = 0.0f, my = 0.0f, mz = 0.0f;
#pragma unroll
  for (int t = 0; t < KSEL; ++t) {
    u32 k = a[t];
    float v = key_to_dist(k);
    float e = __expf((vmin - v) * inv);  // softmax(-v/scale), max-shifted
    float4 o = so[k & 0x7FFu];
    wsum += e;
    mx = fmaf(e, o.x, mx);
    my = fmaf(e, o.y, my);
    mz = fmaf(e, o.z, mz);
  }
  float r = 1.0f / wsum;
  out[3 * n + 0] = px + mx * r;
  out[3 * n + 1] = py + my * r;
  out[3 * n + 2] = pz + mz * r;
}

extern "C" void kernel_launch(void* const* d_in, const int* in_sizes, int n_in,
                              void* d_out, int out_size, void* d_ws,
                              size_t ws_size, hipStream_t stream) {
  const float* means = (const float*)d_in[0];
  const float* nodes = (const float*)d_in[1];
  const float* noffs = (const float*)d_in[2];
  const int* tptr = (const int*)d_in[3];
  int N = in_sizes[0] / 3;  // 131072

  float* sum_ptr = (float*)d_ws;
  u32* keys = (u32*)((char*)d_ws + 256);
  size_t need = 256 + (size_t)N * KSEL * sizeof(u32);

  size_t zbytes = ws_size < 256 ? ws_size : 256;
  if (zbytes) hipMemsetAsync(d_ws, 0, zbytes, stream);

  dim3 blk(256);
  dim3 grid((unsigned)((N + 255) / 256));
  float* out = (float*)d_out;

  if (ws_size >= need) {
    k_select<true><<<grid, blk, 0, stream>>>(means, nodes, keys, sum_ptr, N);
    k_finish<true><<<grid, blk, 0, stream>>>(means, nodes, noffs, tptr, keys,
                                             sum_ptr, out, N);
  } else {
    // ws too small to spill keys: recompute selection in kernel 2
    k_select<false><<<grid, blk, 0, stream>>>(means, nodes, nullptr, sum_ptr, N);
    k_finish<false><<<grid, blk, 0, stream>>>(means, nodes, noffs, tptr, keys,
                                              sum_ptr, out, N);
  }
}

// Round 3
// 175.743 us; speedup vs baseline: 1.7025x; 1.7025x over previous
//
#include <hip/hip_runtime.h>
#include <stdint.h>

#define M_NODES 2048
#define KSEL 16
#define BATCH 16

typedef unsigned int u32;

// ---- stage [2048,3] f32 -> LDS float4 (w=0) ----
__device__ __forceinline__ void stage_nodes(const float* __restrict__ src,
                                            float4* dst) {
  for (int i = threadIdx.x; i < M_NODES; i += blockDim.x) {
    dst[i] = make_float4(src[3 * i + 0], src[3 * i + 1], src[3 * i + 2], 0.0f);
  }
}

// compare-exchange ascending: x=min, y=max (static positions only)
#define CE_ASC(x, y)                    \
  {                                     \
    u32 _a = (x), _b = (y);             \
    (x) = _a < _b ? _a : _b;            \
    (y) = _a < _b ? _b : _a;            \
  }

// ---- branch-free exact top-16: batch-16 bitonic sort + lower-half merge ----
// key = (f32bits(d2) & 0xFFFFF800) | node_idx ; positive-float bits are
// order-preserving, low 11 bits = index (ties -> lowest index, like top_k).
__device__ __forceinline__ void select_top16(float px, float py, float pz,
                                             const float4* sn, u32 a[KSEL]) {
#pragma unroll
  for (int t = 0; t < KSEL; ++t) a[t] = 0xFFFFFFFFu;

#pragma unroll 1
  for (int base = 0; base < M_NODES; base += BATCH) {
    u32 s[BATCH];
    // 1) distances + packed keys for this batch (16 ds_read_b128 + 8 VALU ea)
#pragma unroll
    for (int u = 0; u < BATCH; ++u) {
      float4 n = sn[base + u];
      float dx = px - n.x, dy = py - n.y, dz = pz - n.z;
      float d2 = fmaf(dx, dx, fmaf(dy, dy, dz * dz));
      s[u] = (__float_as_uint(d2) & 0xFFFFF800u) | (u32)(base + u);
    }
    // 2) bitonic sort s ascending (80 compare-exchanges, all static)
#pragma unroll
    for (int k = 2; k <= BATCH; k <<= 1) {
#pragma unroll
      for (int st = k >> 1; st > 0; st >>= 1) {
#pragma unroll
        for (int i = 0; i < BATCH; ++i) {
          int j = i ^ st;
          if (j > i) {
            if ((i & k) == 0) {
              CE_ASC(s[i], s[j])
            } else {
              CE_ASC(s[j], s[i])
            }
          }
        }
      }
    }
    // 3) lower-half of bitonic merge: a asc ++ s desc is bitonic;
    //    min-pair keeps the 16 smallest of the union (bitonic sequence)
#pragma unroll
    for (int i = 0; i < KSEL; ++i) {
      u32 sv = s[KSEL - 1 - i];
      a[i] = a[i] < sv ? a[i] : sv;
    }
    // 4) bitonic clean-up: sort the bitonic a[] ascending (32 CE)
#pragma unroll
    for (int st = 8; st >= 1; st >>= 1) {
#pragma unroll
      for (int i = 0; i < KSEL; ++i) {
        if ((i & st) == 0) {
          CE_ASC(a[i], a[i + st])
        }
      }
    }
  }
}

__device__ __forceinline__ float key_to_dist(u32 k) {
  float v = sqrtf(__uint_as_float(k & 0xFFFFF800u));
  return fmaxf(v, 1e-6f);
}

// ---- kernel 1: top-16 selection, spill keys, accumulate global sum ----
template <bool STORE>
__global__ __launch_bounds__(256) void k_select(
    const float* __restrict__ means, const float* __restrict__ nodes,
    u32* __restrict__ keys_out, float* __restrict__ sum_ptr, int N) {
  __shared__ float4 sn[M_NODES];
  stage_nodes(nodes, sn);
  __syncthreads();

  int n = blockIdx.x * blockDim.x + threadIdx.x;
  float px = means[3 * n + 0];
  float py = means[3 * n + 1];
  float pz = means[3 * n + 2];

  u32 a[KSEL];
  select_top16(px, py, pz, sn, a);

  if (STORE) {
    u32* kp = keys_out + (size_t)n * KSEL;
#pragma unroll
    for (int t = 0; t < KSEL; t += 4) {
      *reinterpret_cast<uint4*>(kp + t) =
          make_uint4(a[t], a[t + 1], a[t + 2], a[t + 3]);
    }
  }

  float s = 0.0f;
#pragma unroll
  for (int t = 0; t < KSEL; ++t) s += key_to_dist(a[t]);
#pragma unroll
  for (int off = 32; off > 0; off >>= 1) s += __shfl_xor(s, off);
  if ((threadIdx.x & 63) == 0) atomicAdd(sum_ptr, s);
}

// ---- kernel 2: global scale -> softmax -> gather offsets -> output ----
template <bool RELOAD>
__global__ __launch_bounds__(256) void k_finish(
    const float* __restrict__ means, const float* __restrict__ nodes,
    const float* __restrict__ noffs, const int* __restrict__ tptr,
    const u32* __restrict__ keys, const float* __restrict__ sum_ptr,
    float* __restrict__ out, int N) {
  __shared__ float4 so[M_NODES];
  int ti = *tptr;
  stage_nodes(noffs + (size_t)ti * (3 * M_NODES), so);

  int n = blockIdx.x * blockDim.x + threadIdx.x;
  float px = means[3 * n + 0];
  float py = means[3 * n + 1];
  float pz = means[3 * n + 2];

  u32 a[KSEL];
  if constexpr (!RELOAD) {
    __shared__ float4 sn[M_NODES];
    stage_nodes(nodes, sn);
    __syncthreads();
    select_top16(px, py, pz, sn, a);
  } else {
    __syncthreads();
    const uint4* kp = reinterpret_cast<const uint4*>(keys + (size_t)n * KSEL);
#pragma unroll
    for (int t = 0; t < 4; ++t) {
      uint4 v = kp[t];
      a[4 * t + 0] = v.x; a[4 * t + 1] = v.y;
      a[4 * t + 2] = v.z; a[4 * t + 3] = v.w;
    }
  }

  float scale = (*sum_ptr) * (1.0f / ((float)N * (float)KSEL)) + 1e-6f;
  float inv = 1.0f / scale;
  float vmin = key_to_dist(a[0]);  // a[] sorted ascending -> a[0] is min

  float wsum = 0.0f, mx = 0.0f, my = 0.0f, mz = 0.0f;
#pragma unroll
  for (int t = 0; t < KSEL; ++t) {
    u32 k = a[t];
    float v = key_to_dist(k);
    float e = __expf((vmin - v) * inv);  // softmax(-v/scale), max-shifted
    float4 o = so[k & 0x7FFu];
    wsum += e;
    mx = fmaf(e, o.x, mx);
    my = fmaf(e, o.y, my);
    mz = fmaf(e, o.z, mz);
  }
  float r = 1.0f / wsum;
  out[3 * n + 0] = px + mx * r;
  out[3 * n + 1] = py + my * r;
  out[3 * n + 2] = pz + mz * r;
}

extern "C" void kernel_launch(void* const* d_in, const int* in_sizes, int n_in,
                              void* d_out, int out_size, void* d_ws,
                              size_t ws_size, hipStream_t stream) {
  const float* means = (const float*)d_in[0];
  const float* nodes = (const float*)d_in[1];
  const float* noffs = (const float*)d_in[2];
  const int* tptr = (const int*)d_in[3];
  int N = in_sizes[0] / 3;  // 131072

  float* sum_ptr = (float*)d_ws;
  u32* keys = (u32*)((char*)d_ws + 256);
  size_t need = 256 + (size_t)N * KSEL * sizeof(u32);

  size_t zbytes = ws_size < 256 ? ws_size : 256;
  if (zbytes) hipMemsetAsync(d_ws, 0, zbytes, stream);

  dim3 blk(256);
  dim3 grid((unsigned)((N + 255) / 256));
  float* out = (float*)d_out;

  if (ws_size >= need) {
    k_select<true><<<grid, blk, 0, stream>>>(means, nodes, keys, sum_ptr, N);
    k_finish<true><<<grid, blk, 0, stream>>>(means, nodes, noffs, tptr, keys,
                                             sum_ptr, out, N);
  } else {
    // ws too small to spill keys: recompute selection in kernel 2
    k_select<false><<<grid, blk, 0, stream>>>(means, nodes, nullptr, sum_ptr, N);
    k_finish<false><<<grid, blk, 0, stream>>>(means, nodes, noffs, tptr, keys,
                                              sum_ptr, out, N);
  }
}

// Round 4
// 162.611 us; speedup vs baseline: 1.8400x; 1.0808x over previous
//
#include <hip/hip_runtime.h>
#include <stdint.h>

#define M_NODES 2048
#define KSEL 16
#define BATCH 16

typedef unsigned int u32;

// ---- stage [2048,3] f32 -> LDS float4 (w=0) ----
__device__ __forceinline__ void stage_nodes(const float* __restrict__ src,
                                            float4* dst) {
  for (int i = threadIdx.x; i < M_NODES; i += blockDim.x) {
    dst[i] = make_float4(src[3 * i + 0], src[3 * i + 1], src[3 * i + 2], 0.0f);
  }
}

// compare-exchange ascending: x=min, y=max (static positions only)
#define CE_ASC(x, y)                    \
  {                                     \
    u32 _a = (x), _b = (y);             \
    (x) = _a < _b ? _a : _b;            \
    (y) = _a < _b ? _b : _a;            \
  }

// sort s[16] ascending with a bitonic network (80 CE, all static indices)
__device__ __forceinline__ void sort16(u32 s[BATCH]) {
#pragma unroll
  for (int k = 2; k <= BATCH; k <<= 1) {
#pragma unroll
    for (int st = k >> 1; st > 0; st >>= 1) {
#pragma unroll
      for (int i = 0; i < BATCH; ++i) {
        int j = i ^ st;
        if (j > i) {
          if ((i & k) == 0) {
            CE_ASC(s[i], s[j])
          } else {
            CE_ASC(s[j], s[i])
          }
        }
      }
    }
  }
}

// merge sorted-asc batch s (descending-paired) into sorted-asc a (in place)
__device__ __forceinline__ void merge_into(u32 a[KSEL], const u32 s[BATCH]) {
#pragma unroll
  for (int i = 0; i < KSEL; ++i) {
    u32 sv = s[KSEL - 1 - i];
    a[i] = a[i] < sv ? a[i] : sv;  // a becomes bitonic: 16 smallest of union
  }
#pragma unroll
  for (int st = 8; st >= 1; st >>= 1) {  // bitonic clean-up -> ascending
#pragma unroll
    for (int i = 0; i < KSEL; ++i) {
      if ((i & st) == 0) {
        CE_ASC(a[i], a[i + st])
      }
    }
  }
}

// ---- per-lane exact top-16 over nodes j = base + STRIDE*u + c ----
// key = (f32bits(d2) & 0xFFFFF800) | node_idx ; positive-float bits are
// order-preserving, low 11 bits = index (ties -> lowest index, like top_k).
template <int STRIDE, int COUNT>
__device__ __forceinline__ void select_top16(float px, float py, float pz,
                                             const float4* sn, u32 a[KSEL],
                                             int c) {
#pragma unroll
  for (int t = 0; t < KSEL; ++t) a[t] = 0xFFFFFFFFu;

#pragma unroll 1
  for (int base = 0; base < COUNT; base += BATCH * STRIDE) {
    u32 s[BATCH];
#pragma unroll
    for (int u = 0; u < BATCH; ++u) {
      int j = base + STRIDE * u + c;
      float4 n = sn[j];
      float dx = px - n.x, dy = py - n.y, dz = pz - n.z;
      float d2 = fmaf(dx, dx, fmaf(dy, dy, dz * dz));
      s[u] = (__float_as_uint(d2) & 0xFFFFF800u) | (u32)j;
    }
    sort16(s);
    merge_into(a, s);
  }
}

// cross-lane merge: combine sorted lists of lane l and lane l^mask;
// both lanes end with the identical merged sorted-asc top-16.
__device__ __forceinline__ void merge_lanes(u32 a[KSEL], int mask) {
  u32 b[KSEL];
#pragma unroll
  for (int i = 0; i < KSEL; ++i) b[i] = __shfl_xor(a[KSEL - 1 - i], mask);
#pragma unroll
  for (int i = 0; i < KSEL; ++i) a[i] = a[i] < b[i] ? a[i] : b[i];
#pragma unroll
  for (int st = 8; st >= 1; st >>= 1) {
#pragma unroll
    for (int i = 0; i < KSEL; ++i) {
      if ((i & st) == 0) {
        CE_ASC(a[i], a[i + st])
      }
    }
  }
}

__device__ __forceinline__ float key_to_dist(u32 k) {
  float v = sqrtf(__uint_as_float(k & 0xFFFFF800u));
  return fmaxf(v, 1e-6f);
}

// ---- kernel 1: 4 threads per point, top-16 + spill keys + global sum ----
template <bool STORE>
__global__ __launch_bounds__(256, 8) void k_select(
    const float* __restrict__ means, const float* __restrict__ nodes,
    u32* __restrict__ keys_out, float* __restrict__ sum_ptr, int N) {
  __shared__ float4 sn[M_NODES];
  stage_nodes(nodes, sn);
  __syncthreads();

  int tid = blockIdx.x * blockDim.x + threadIdx.x;
  int n = tid >> 2;        // point index
  int c = tid & 3;         // slice: nodes j with j % 4 == c
  float px = means[3 * n + 0];
  float py = means[3 * n + 1];
  float pz = means[3 * n + 2];

  u32 a[KSEL];
  select_top16<4, M_NODES>(px, py, pz, sn, a, c);
  merge_lanes(a, 1);
  merge_lanes(a, 2);  // all 4 lanes now hold the exact global top-16

  if (STORE && c == 0) {
    u32* kp = keys_out + (size_t)n * KSEL;
#pragma unroll
    for (int t = 0; t < KSEL; t += 4) {
      *reinterpret_cast<uint4*>(kp + t) =
          make_uint4(a[t], a[t + 1], a[t + 2], a[t + 3]);
    }
  }

  float s = 0.0f;
#pragma unroll
  for (int t = 0; t < KSEL; ++t) s += key_to_dist(a[t]);
#pragma unroll
  for (int off = 32; off > 0; off >>= 1) s += __shfl_xor(s, off);
  if ((threadIdx.x & 63) == 0) atomicAdd(sum_ptr, 0.25f * s);  // 4x duplicate
}

// ---- kernel 2: global scale -> softmax -> gather offsets -> output ----
template <bool RELOAD>
__global__ __launch_bounds__(256) void k_finish(
    const float* __restrict__ means, const float* __restrict__ nodes,
    const float* __restrict__ noffs, const int* __restrict__ tptr,
    const u32* __restrict__ keys, const float* __restrict__ sum_ptr,
    float* __restrict__ out, int N) {
  __shared__ float4 so[M_NODES];
  int ti = *tptr;
  stage_nodes(noffs + (size_t)ti * (3 * M_NODES), so);

  int n = blockIdx.x * blockDim.x + threadIdx.x;
  float px = means[3 * n + 0];
  float py = means[3 * n + 1];
  float pz = means[3 * n + 2];

  u32 a[KSEL];
  if constexpr (!RELOAD) {
    __shared__ float4 sn[M_NODES];
    stage_nodes(nodes, sn);
    __syncthreads();
    select_top16<1, M_NODES>(px, py, pz, sn, a, 0);
  } else {
    __syncthreads();
    const uint4* kp = reinterpret_cast<const uint4*>(keys + (size_t)n * KSEL);
#pragma unroll
    for (int t = 0; t < 4; ++t) {
      uint4 v = kp[t];
      a[4 * t + 0] = v.x; a[4 * t + 1] = v.y;
      a[4 * t + 2] = v.z; a[4 * t + 3] = v.w;
    }
  }

  float scale = (*sum_ptr) * (1.0f / ((float)N * (float)KSEL)) + 1e-6f;
  float inv = 1.0f / scale;
  float vmin = key_to_dist(a[0]);  // a[] sorted ascending -> a[0] is min

  float wsum = 0.0f, mx = 0.0f, my = 0.0f, mz = 0.0f;
#pragma unroll
  for (int t = 0; t < KSEL; ++t) {
    u32 k = a[t];
    float v = key_to_dist(k);
    float e = __expf((vmin - v) * inv);  // softmax(-v/scale), max-shifted
    float4 o = so[k & 0x7FFu];
    wsum += e;
    mx = fmaf(e, o.x, mx);
    my = fmaf(e, o.y, my);
    mz = fmaf(e, o.z, mz);
  }
  float r = 1.0f / wsum;
  out[3 * n + 0] = px + mx * r;
  out[3 * n + 1] = py + my * r;
  out[3 * n + 2] = pz + mz * r;
}

extern "C" void kernel_launch(void* const* d_in, const int* in_sizes, int n_in,
                              void* d_out, int out_size, void* d_ws,
                              size_t ws_size, hipStream_t stream) {
  const float* means = (const float*)d_in[0];
  const float* nodes = (const float*)d_in[1];
  const float* noffs = (const float*)d_in[2];
  const int* tptr = (const int*)d_in[3];
  int N = in_sizes[0] / 3;  // 131072

  float* sum_ptr = (float*)d_ws;
  u32* keys = (u32*)((char*)d_ws + 256);
  size_t need = 256 + (size_t)N * KSEL * sizeof(u32);

  size_t zbytes = ws_size < 256 ? ws_size : 256;
  if (zbytes) hipMemsetAsync(d_ws, 0, zbytes, stream);

  dim3 blk(256);
  float* out = (float*)d_out;

  if (ws_size >= need) {
    dim3 grid_sel((unsigned)(((size_t)N * 4 + 255) / 256));  // 4 threads/point
    dim3 grid_fin((unsigned)((N + 255) / 256));
    k_select<true><<<grid_sel, blk, 0, stream>>>(means, nodes, keys, sum_ptr, N);
    k_finish<true><<<grid_fin, blk, 0, stream>>>(means, nodes, noffs, tptr,
                                                 keys, sum_ptr, out, N);
  } else {
    // ws too small to spill keys: recompute selection in kernel 2
    dim3 grid_sel((unsigned)(((size_t)N * 4 + 255) / 256));
    dim3 grid_fin((unsigned)((N + 255) / 256));
    k_select<false><<<grid_sel, blk, 0, stream>>>(means, nodes, nullptr,
                                                  sum_ptr, N);
    k_finish<false><<<grid_fin, blk, 0, stream>>>(means, nodes, noffs, tptr,
                                                  keys, sum_ptr, out, N);
  }
}

// Round 5
// 154.916 us; speedup vs baseline: 1.9313x; 1.0497x over previous
//
#include <hip/hip_runtime.h>
#include <stdint.h>

#define M_NODES 2048
#define KSEL 16
#define BATCH 16

typedef unsigned int u32;

// ---- stage [2048,3] f32 -> LDS float4 (x,y,z,w) ----
// W_NN: w = |n|^2 (for dot-form distance); else w = 0.
template <bool W_NN>
__device__ __forceinline__ void stage_nodes(const float* __restrict__ src,
                                            float4* dst) {
  for (int i = threadIdx.x; i < M_NODES; i += blockDim.x) {
    float x = src[3 * i + 0], y = src[3 * i + 1], z = src[3 * i + 2];
    float w = W_NN ? fmaf(x, x, fmaf(y, y, z * z)) : 0.0f;
    dst[i] = make_float4(x, y, z, w);
  }
}

// compare-exchange ascending (explicit min/max -> v_min_u32/v_max_u32)
#define CE_ASC(x, y)                    \
  {                                     \
    u32 _a = (x), _b = (y);             \
    (x) = min(_a, _b);                  \
    (y) = max(_a, _b);                  \
  }

// Batcher odd-even mergesort, n=16: 63 CE, ascending. All indices static.
__device__ __forceinline__ void sort16(u32 s[BATCH]) {
#pragma unroll
  for (int p = 1; p < BATCH; p <<= 1) {
#pragma unroll
    for (int k = p; k >= 1; k >>= 1) {
#pragma unroll
      for (int j = k & (p - 1); j + k < BATCH; j += 2 * k) {
#pragma unroll
        for (int i = 0; i < k; ++i) {
          if ((i + j) / (2 * p) == (i + j + k) / (2 * p)) {
            CE_ASC(s[i + j], s[i + j + k])
          }
        }
      }
    }
  }
}

// merge sorted-asc batch s into sorted-asc a (keep 16 smallest of union)
__device__ __forceinline__ void merge_into(u32 a[KSEL], const u32 s[BATCH]) {
#pragma unroll
  for (int i = 0; i < KSEL; ++i) {
    u32 sv = s[KSEL - 1 - i];
    a[i] = min(a[i], sv);  // a becomes bitonic: 16 smallest of union
  }
#pragma unroll
  for (int st = 8; st >= 1; st >>= 1) {  // bitonic clean-up -> ascending
#pragma unroll
    for (int i = 0; i < KSEL; ++i) {
      if ((i & st) == 0) {
        CE_ASC(a[i], a[i + st])
      }
    }
  }
}

// ---- per-lane exact top-16 over nodes j = 64*b + 4*u + c (slice c of 4) ----
// key = (f32bits(d2) & 0xFFFFF800) | j ; positive-float bits are order-
// preserving, low 11 bits = index (ties -> lowest index, like top_k).
// d2 via reference's expanded form: |p|^2 + |n|^2 - 2 p.n  (w holds |n|^2).
__device__ __forceinline__ void select_top16(float ax, float ay, float az,
                                             float pp, const float4* sn,
                                             u32 a[KSEL], int c) {
#pragma unroll
  for (int t = 0; t < KSEL; ++t) a[t] = 0xFFFFFFFFu;

#pragma unroll 1
  for (int ob = 0; ob < M_NODES / (4 * 64); ++ob) {  // 8 outer blocks
#pragma unroll
    for (int b = 0; b < 4; ++b) {  // 4 batches, compile-time offsets
      u32 s[BATCH];
#pragma unroll
      for (int u = 0; u < BATCH; ++u) {
        int j = (ob * 4 + b) * 64 + 4 * u + c;
        float4 n = sn[(ob * 4 + b) * 64 + 4 * u + c];
        float d2 = fmaf(n.x, ax, fmaf(n.y, ay, fmaf(n.z, az, n.w + pp)));
        d2 = fmaxf(d2, 0.0f);  // guard cancellation (ref clamps too)
        s[u] = (__float_as_uint(d2) & 0xFFFFF800u) | (u32)j;
      }
      sort16(s);
      merge_into(a, s);
    }
  }
}

// cross-lane merge: combine sorted lists of lane l and lane l^mask;
// both lanes end with the identical merged sorted-asc top-16.
__device__ __forceinline__ void merge_lanes(u32 a[KSEL], int mask) {
  u32 b[KSEL];
#pragma unroll
  for (int i = 0; i < KSEL; ++i) b[i] = __shfl_xor(a[KSEL - 1 - i], mask);
#pragma unroll
  for (int i = 0; i < KSEL; ++i) a[i] = min(a[i], b[i]);
#pragma unroll
  for (int st = 8; st >= 1; st >>= 1) {
#pragma unroll
    for (int i = 0; i < KSEL; ++i) {
      if ((i & st) == 0) {
        CE_ASC(a[i], a[i + st])
      }
    }
  }
}

__device__ __forceinline__ float key_to_dist(u32 k) {
  float v = sqrtf(__uint_as_float(k & 0xFFFFF800u));
  return fmaxf(v, 1e-6f);
}

// ---- kernel 1: 4 threads per point, top-16 + spill keys + global sum ----
template <bool STORE>
__global__ __launch_bounds__(256, 8) void k_select(
    const float* __restrict__ means, const float* __restrict__ nodes,
    u32* __restrict__ keys_out, float* __restrict__ sum_ptr, int N) {
  __shared__ float4 sn[M_NODES];
  stage_nodes<true>(nodes, sn);
  __syncthreads();

  int tid = blockIdx.x * blockDim.x + threadIdx.x;
  int n = tid >> 2;        // point index
  int c = tid & 3;         // slice: nodes j with j % 4 == c
  float px = means[3 * n + 0];
  float py = means[3 * n + 1];
  float pz = means[3 * n + 2];
  float pp = fmaf(px, px, fmaf(py, py, pz * pz));

  u32 a[KSEL];
  select_top16(-2.0f * px, -2.0f * py, -2.0f * pz, pp, sn, a, c);
  merge_lanes(a, 1);
  merge_lanes(a, 2);  // all 4 lanes now hold the exact global top-16

  if (STORE && c == 0) {
    u32* kp = keys_out + (size_t)n * KSEL;
#pragma unroll
    for (int t = 0; t < KSEL; t += 4) {
      *reinterpret_cast<uint4*>(kp + t) =
          make_uint4(a[t], a[t + 1], a[t + 2], a[t + 3]);
    }
  }

  float s = 0.0f;
#pragma unroll
  for (int t = 0; t < KSEL; ++t) s += key_to_dist(a[t]);
#pragma unroll
  for (int off = 32; off > 0; off >>= 1) s += __shfl_xor(s, off);
  if ((threadIdx.x & 63) == 0) atomicAdd(sum_ptr, 0.25f * s);  // 4x duplicate
}

// ---- kernel 2: global scale -> softmax -> gather offsets -> output ----
template <bool RELOAD>
__global__ __launch_bounds__(256) void k_finish(
    const float* __restrict__ means, const float* __restrict__ nodes,
    const float* __restrict__ noffs, const int* __restrict__ tptr,
    const u32* __restrict__ keys, const float* __restrict__ sum_ptr,
    float* __restrict__ out, int N) {
  __shared__ float4 so[M_NODES];
  int ti = *tptr;
  stage_nodes<false>(noffs + (size_t)ti * (3 * M_NODES), so);

  int n = blockIdx.x * blockDim.x + threadIdx.x;
  float px = means[3 * n + 0];
  float py = means[3 * n + 1];
  float pz = means[3 * n + 2];

  u32 a[KSEL];
  if constexpr (!RELOAD) {
    __shared__ float4 sn[M_NODES];
    stage_nodes<true>(nodes, sn);
    __syncthreads();
    float pp = fmaf(px, px, fmaf(py, py, pz * pz));
    // single-thread-per-point fallback: 4 interleaved slices done serially
    u32 tmp[KSEL];
    select_top16(-2.0f * px, -2.0f * py, -2.0f * pz, pp, sn, a, 0);
#pragma unroll 1
    for (int c = 1; c < 4; ++c) {
      select_top16(-2.0f * px, -2.0f * py, -2.0f * pz, pp, sn, tmp, c);
      merge_into(a, tmp);
    }
  } else {
    __syncthreads();
    const uint4* kp = reinterpret_cast<const uint4*>(keys + (size_t)n * KSEL);
#pragma unroll
    for (int t = 0; t < 4; ++t) {
      uint4 v = kp[t];
      a[4 * t + 0] = v.x; a[4 * t + 1] = v.y;
      a[4 * t + 2] = v.z; a[4 * t + 3] = v.w;
    }
  }

  float scale = (*sum_ptr) * (1.0f / ((float)N * (float)KSEL)) + 1e-6f;
  float inv = 1.0f / scale;
  float vmin = key_to_dist(a[0]);  // a[] sorted ascending -> a[0] is min

  float wsum = 0.0f, mx = 0.0f, my = 0.0f, mz = 0.0f;
#pragma unroll
  for (int t = 0; t < KSEL; ++t) {
    u32 k = a[t];
    float v = key_to_dist(k);
    float e = __expf((vmin - v) * inv);  // softmax(-v/scale), max-shifted
    float4 o = so[k & 0x7FFu];
    wsum += e;
    mx = fmaf(e, o.x, mx);
    my = fmaf(e, o.y, my);
    mz = fmaf(e, o.z, mz);
  }
  float r = 1.0f / wsum;
  out[3 * n + 0] = px + mx * r;
  out[3 * n + 1] = py + my * r;
  out[3 * n + 2] = pz + mz * r;
}

extern "C" void kernel_launch(void* const* d_in, const int* in_sizes, int n_in,
                              void* d_out, int out_size, void* d_ws,
                              size_t ws_size, hipStream_t stream) {
  const float* means = (const float*)d_in[0];
  const float* nodes = (const float*)d_in[1];
  const float* noffs = (const float*)d_in[2];
  const int* tptr = (const int*)d_in[3];
  int N = in_sizes[0] / 3;  // 131072

  float* sum_ptr = (float*)d_ws;
  u32* keys = (u32*)((char*)d_ws + 256);
  size_t need = 256 + (size_t)N * KSEL * sizeof(u32);

  size_t zbytes = ws_size < 256 ? ws_size : 256;
  if (zbytes) hipMemsetAsync(d_ws, 0, zbytes, stream);

  dim3 blk(256);
  dim3 grid_sel((unsigned)(((size_t)N * 4 + 255) / 256));  // 4 threads/point
  dim3 grid_fin((unsigned)((N + 255) / 256));
  float* out = (float*)d_out;

  if (ws_size >= need) {
    k_select<true><<<grid_sel, blk, 0, stream>>>(means, nodes, keys, sum_ptr, N);
    k_finish<true><<<grid_fin, blk, 0, stream>>>(means, nodes, noffs, tptr,
                                                 keys, sum_ptr, out, N);
  } else {
    // ws too small to spill keys: recompute selection in kernel 2
    k_select<false><<<grid_sel, blk, 0, stream>>>(means, nodes, nullptr,
                                                  sum_ptr, N);
    k_finish<false><<<grid_fin, blk, 0, stream>>>(means, nodes, noffs, tptr,
                                                  keys, sum_ptr, out, N);
  }
}

// Round 6
// 130.026 us; speedup vs baseline: 2.3011x; 1.1914x over previous
//
#include <hip/hip_runtime.h>
#include <stdint.h>

#define M_NODES 2048
#define KSEL 16
#define BATCH 16

typedef unsigned int u32;

// compare-exchange ascending (explicit min/max -> v_min_u32/v_max_u32)
#define CE_ASC(x, y)                    \
  {                                     \
    u32 _a = (x), _b = (y);             \
    (x) = min(_a, _b);                  \
    (y) = max(_a, _b);                  \
  }

// Batcher odd-even mergesort, n=16: 63 CE, ascending. All indices static.
__device__ __forceinline__ void sort16(u32 s[BATCH]) {
#pragma unroll
  for (int p = 1; p < BATCH; p <<= 1) {
#pragma unroll
    for (int k = p; k >= 1; k >>= 1) {
#pragma unroll
      for (int j = k & (p - 1); j + k < BATCH; j += 2 * k) {
#pragma unroll
        for (int i = 0; i < k; ++i) {
          if ((i + j) / (2 * p) == (i + j + k) / (2 * p)) {
            CE_ASC(s[i + j], s[i + j + k])
          }
        }
      }
    }
  }
}

// merge sorted-asc batch s into sorted-asc a (keep 16 smallest of union)
__device__ __forceinline__ void merge_into(u32 a[KSEL], const u32 s[BATCH]) {
#pragma unroll
  for (int i = 0; i < KSEL; ++i) {
    u32 sv = s[KSEL - 1 - i];
    a[i] = min(a[i], sv);  // a becomes bitonic: 16 smallest of union
  }
#pragma unroll
  for (int st = 8; st >= 1; st >>= 1) {  // bitonic clean-up -> ascending
#pragma unroll
    for (int i = 0; i < KSEL; ++i) {
      if ((i & st) == 0) {
        CE_ASC(a[i], a[i + st])
      }
    }
  }
}

// ---- exact top-16 over nodes [jbase, jbase + 16*nbatch), jbase uniform ----
// All lanes process the SAME node j each step -> node coords are wave-uniform
// -> compiler emits s_load (scalar pipe, no LDS / no per-lane VMEM).
// key = (f32bits(d2) & 0xFFFFF800) | j ; positive-float bits are order-
// preserving, low 11 bits = index (ties -> lowest index, like top_k).
__device__ __forceinline__ void select_scalar(float px, float py, float pz,
                                              const float* __restrict__ nodes,
                                              u32 a[KSEL], int jbase,
                                              int nbatch) {
#pragma unroll
  for (int t = 0; t < KSEL; ++t) a[t] = 0xFFFFFFFFu;

#pragma unroll 1
  for (int b = 0; b < nbatch; ++b) {
    int j0 = jbase + BATCH * b;                  // wave-uniform
    const float* np = nodes + 3 * j0;
    u32 s[BATCH];
#pragma unroll
    for (int u = 0; u < BATCH; ++u) {
      float nx = np[3 * u + 0];                  // uniform -> SGPR
      float ny = np[3 * u + 1];
      float nz = np[3 * u + 2];
      float dx = px - nx, dy = py - ny, dz = pz - nz;
      float d2 = fmaf(dx, dx, fmaf(dy, dy, dz * dz));  // >= 0 always
      s[u] = (__float_as_uint(d2) & 0xFFFFF800u) | (u32)(j0 + u);
    }
    sort16(s);
    merge_into(a, s);
  }
}

__device__ __forceinline__ float key_to_dist(u32 k) {
  float v = sqrtf(__uint_as_float(k & 0xFFFFF800u));
  return fmaxf(v, 1e-6f);
}

// ---- kernel 1: block = 64 points x 4 waves; wave w scans nodes [512w,512w+512)
// via scalar loads; partial top-16s merged through small LDS scratch. ----
template <bool STORE>
__global__ __launch_bounds__(256, 8) void k_select(
    const float* __restrict__ means, const float* __restrict__ nodes,
    u32* __restrict__ keys_out, float* __restrict__ sum_ptr, int N) {
  // [3 writer waves][64 lanes][16 keys], row padded to 17 for bank spread
  __shared__ u32 lists[3][64][KSEL + 1];

  int lane = threadIdx.x & 63;
  int w = __builtin_amdgcn_readfirstlane((int)(threadIdx.x >> 6));
  int n = blockIdx.x * 64 + lane;

  float px = means[3 * n + 0];
  float py = means[3 * n + 1];
  float pz = means[3 * n + 2];

  u32 a[KSEL];
  select_scalar(px, py, pz, nodes, a, 512 * w, 512 / BATCH);

  if (w != 0) {
#pragma unroll
    for (int t = 0; t < KSEL; ++t) lists[w - 1][lane][t] = a[t];
  }
  __syncthreads();
  if (w != 0) return;  // waves 1..3 done

  // wave 0: merge the 3 partner lists -> exact global top-16 per point
#pragma unroll 1
  for (int i = 0; i < 3; ++i) {
    u32 b[KSEL];
#pragma unroll
    for (int t = 0; t < KSEL; ++t) b[t] = lists[i][lane][t];
    merge_into(a, b);
  }

  if (STORE) {
    u32* kp = keys_out + (size_t)n * KSEL;
#pragma unroll
    for (int t = 0; t < KSEL; t += 4) {
      *reinterpret_cast<uint4*>(kp + t) =
          make_uint4(a[t], a[t + 1], a[t + 2], a[t + 3]);
    }
  }

  float s = 0.0f;
#pragma unroll
  for (int t = 0; t < KSEL; ++t) s += key_to_dist(a[t]);
#pragma unroll
  for (int off = 32; off > 0; off >>= 1) s += __shfl_xor(s, off);
  if (lane == 0) atomicAdd(sum_ptr, s);
}

// ---- kernel 2: global scale -> softmax -> gather offsets -> output ----
template <bool RELOAD>
__global__ __launch_bounds__(256) void k_finish(
    const float* __restrict__ means, const float* __restrict__ nodes,
    const float* __restrict__ noffs, const int* __restrict__ tptr,
    const u32* __restrict__ keys, const float* __restrict__ sum_ptr,
    float* __restrict__ out, int N) {
  __shared__ float4 so[M_NODES];
  int ti = *tptr;
  {
    const float* src = noffs + (size_t)ti * (3 * M_NODES);
    for (int i = threadIdx.x; i < M_NODES; i += blockDim.x) {
      so[i] = make_float4(src[3 * i + 0], src[3 * i + 1], src[3 * i + 2], 0.0f);
    }
  }
  __syncthreads();

  int n = blockIdx.x * blockDim.x + threadIdx.x;
  float px = means[3 * n + 0];
  float py = means[3 * n + 1];
  float pz = means[3 * n + 2];

  u32 a[KSEL];
  if constexpr (!RELOAD) {
    // fallback (ws too small for key spill): full rescan, scalar path
    select_scalar(px, py, pz, nodes, a, 0, M_NODES / BATCH);
  } else {
    const uint4* kp = reinterpret_cast<const uint4*>(keys + (size_t)n * KSEL);
#pragma unroll
    for (int t = 0; t < 4; ++t) {
      uint4 v = kp[t];
      a[4 * t + 0] = v.x; a[4 * t + 1] = v.y;
      a[4 * t + 2] = v.z; a[4 * t + 3] = v.w;
    }
  }

  float scale = (*sum_ptr) * (1.0f / ((float)N * (float)KSEL)) + 1e-6f;
  float inv = 1.0f / scale;
  float vmin = key_to_dist(a[0]);  // a[] sorted ascending -> a[0] is min

  float wsum = 0.0f, mx = 0.0f, my = 0.0f, mz = 0.0f;
#pragma unroll
  for (int t = 0; t < KSEL; ++t) {
    u32 k = a[t];
    float v = key_to_dist(k);
    float e = __expf((vmin - v) * inv);  // softmax(-v/scale), max-shifted
    float4 o = so[k & 0x7FFu];
    wsum += e;
    mx = fmaf(e, o.x, mx);
    my = fmaf(e, o.y, my);
    mz = fmaf(e, o.z, mz);
  }
  float r = 1.0f / wsum;
  out[3 * n + 0] = px + mx * r;
  out[3 * n + 1] = py + my * r;
  out[3 * n + 2] = pz + mz * r;
}

extern "C" void kernel_launch(void* const* d_in, const int* in_sizes, int n_in,
                              void* d_out, int out_size, void* d_ws,
                              size_t ws_size, hipStream_t stream) {
  const float* means = (const float*)d_in[0];
  const float* nodes = (const float*)d_in[1];
  const float* noffs = (const float*)d_in[2];
  const int* tptr = (const int*)d_in[3];
  int N = in_sizes[0] / 3;  // 131072

  float* sum_ptr = (float*)d_ws;
  u32* keys = (u32*)((char*)d_ws + 256);
  size_t need = 256 + (size_t)N * KSEL * sizeof(u32);

  size_t zbytes = ws_size < 256 ? ws_size : 256;
  if (zbytes) hipMemsetAsync(d_ws, 0, zbytes, stream);

  dim3 blk(256);
  dim3 grid_sel((unsigned)((N + 63) / 64));     // 64 points per block
  dim3 grid_fin((unsigned)((N + 255) / 256));
  float* out = (float*)d_out;

  if (ws_size >= need) {
    k_select<true><<<grid_sel, blk, 0, stream>>>(means, nodes, keys, sum_ptr, N);
    k_finish<true><<<grid_fin, blk, 0, stream>>>(means, nodes, noffs, tptr,
                                                 keys, sum_ptr, out, N);
  } else {
    // ws too small to spill keys: recompute selection in kernel 2
    k_select<false><<<grid_sel, blk, 0, stream>>>(means, nodes, nullptr,
                                                  sum_ptr, N);
    k_finish<false><<<grid_fin, blk, 0, stream>>>(means, nodes, noffs, tptr,
                                                  keys, sum_ptr, out, N);
  }
}